// Round 3
// baseline (116.355 us; speedup 1.0000x reference)
//
#include <hip/hip_runtime.h>
#include <math.h>

// Problem: B=65536 rows, N=1024 cols, fp32.
//   t_b = argmax_c target[b,c]  (first-max tie-break, jnp.argmax semantics)
//   out = mean_b( -log(y[b,t_b] + 1e-8) ) + sum_{b,c} w[popc(t_b ^ c)] * y[b,c] / (B*N)
//   w[p] = (p==0) ? 0 : 6^p
// Memory-bound: 512 MB read once -> ~81 us roofline at 6.3 TB/s.

#define B_ROWS 65536
#define N_COLS 1024
#define WAVES_PER_BLOCK 4
#define ROWS_BLOCKS 2048
#define ROWS_THREADS (WAVES_PER_BLOCK * 64)

__global__ __launch_bounds__(ROWS_THREADS)
void ce_rows_kernel(const float* __restrict__ y_true,
                    const float* __restrict__ target,
                    float* __restrict__ partials) {
    __shared__ float w_lds[16];
    __shared__ float wave_part[WAVES_PER_BLOCK];

    const int tid = threadIdx.x;
    if (tid < 11) {
        // w_lds[p] = p==0 ? 0 : 6^p (exact in fp32 up to 6^10 = 60466176 < 2^26)
        float w = 1.0f;
        for (int p = 0; p < tid; ++p) w *= 6.0f;
        w_lds[tid] = (tid == 0) ? 0.0f : w;
    }
    __syncthreads();

    const int lane = tid & 63;
    const int wid  = tid >> 6;
    const int gwave  = blockIdx.x * WAVES_PER_BLOCK + wid;
    const int nwaves = gridDim.x * WAVES_PER_BLOCK;

    const float invB  = 1.0f / (float)B_ROWS;
    const float invBN = 1.0f / ((float)B_ROWS * (float)N_COLS);

    float acc = 0.0f;  // per-lane copy of this wave's partial (identical across lanes)

    for (int row = gwave; row < B_ROWS; row += nwaves) {
        // ---- pass 1: argmax of target row (64 lanes x 16 elems) ----
        const float4* trow = (const float4*)(target + (size_t)row * N_COLS);
        float bestv = -1.0f;   // inputs are uniform [0,1) => >= 0
        int   besti = 0;
        #pragma unroll
        for (int k = 0; k < 4; ++k) {
            const int j  = lane + 64 * k;     // float4 index; coalesced across wave
            const float4 v = trow[j];
            const int c0 = j * 4;
            // first-index tie-break: strictly-greater OR (equal AND smaller idx)
            if (v.x > bestv || (v.x == bestv && c0     < besti)) { bestv = v.x; besti = c0;     }
            if (v.y > bestv || (v.y == bestv && c0 + 1 < besti)) { bestv = v.y; besti = c0 + 1; }
            if (v.z > bestv || (v.z == bestv && c0 + 2 < besti)) { bestv = v.z; besti = c0 + 2; }
            if (v.w > bestv || (v.w == bestv && c0 + 3 < besti)) { bestv = v.w; besti = c0 + 3; }
        }
        #pragma unroll
        for (int m = 32; m >= 1; m >>= 1) {
            const float ov = __shfl_xor(bestv, m, 64);
            const int   oi = __shfl_xor(besti, m, 64);
            if (ov > bestv || (ov == bestv && oi < besti)) { bestv = ov; besti = oi; }
        }
        const int t = besti;  // uniform across wave

        // ---- pass 2: weighted sum of y_true row + extract y[t] ----
        const float4* yrow = (const float4*)(y_true + (size_t)row * N_COLS);
        float pt = 0.0f;
        float yt = 0.0f;
        #pragma unroll
        for (int k = 0; k < 4; ++k) {
            const int j  = lane + 64 * k;
            const float4 v = yrow[j];
            const int c0 = j * 4;
            const float w0 = w_lds[__popc(t ^ c0)];        // popc(t^t)=0 -> w=0 excludes target class
            const float w1 = w_lds[__popc(t ^ (c0 + 1))];
            const float w2 = w_lds[__popc(t ^ (c0 + 2))];
            const float w3 = w_lds[__popc(t ^ (c0 + 3))];
            pt += w0 * v.x + w1 * v.y + w2 * v.z + w3 * v.w;
            if (t >= c0 && t < c0 + 4) {
                yt = (t == c0) ? v.x : (t == c0 + 1) ? v.y : (t == c0 + 2) ? v.z : v.w;
            }
        }
        #pragma unroll
        for (int m = 32; m >= 1; m >>= 1) {
            pt += __shfl_xor(pt, m, 64);
            yt += __shfl_xor(yt, m, 64);   // exactly one lane nonzero
        }
        acc += -logf(yt + 1e-8f) * invB + pt * invBN;
    }

    if (lane == 0) wave_part[wid] = acc;
    __syncthreads();
    if (tid == 0) {
        float s = 0.0f;
        #pragma unroll
        for (int w = 0; w < WAVES_PER_BLOCK; ++w) s += wave_part[w];
        partials[blockIdx.x] = s;
    }
}

__global__ __launch_bounds__(256)
void ce_reduce_kernel(const float* __restrict__ partials, int n, float* __restrict__ out) {
    __shared__ float s[256];
    const int tid = threadIdx.x;
    float a = 0.0f;
    for (int i = tid; i < n; i += 256) a += partials[i];  // fixed order -> deterministic
    s[tid] = a;
    __syncthreads();
    for (int off = 128; off > 0; off >>= 1) {
        if (tid < off) s[tid] += s[tid + off];
        __syncthreads();
    }
    if (tid == 0) out[0] = s[0];
}

extern "C" void kernel_launch(void* const* d_in, const int* in_sizes, int n_in,
                              void* d_out, int out_size, void* d_ws, size_t ws_size,
                              hipStream_t stream) {
    const float* y_true = (const float*)d_in[0];
    const float* target = (const float*)d_in[1];
    float* out = (float*)d_out;
    float* partials = (float*)d_ws;  // ROWS_BLOCKS floats = 8 KB

    ce_rows_kernel<<<ROWS_BLOCKS, ROWS_THREADS, 0, stream>>>(y_true, target, partials);
    ce_reduce_kernel<<<1, 256, 0, stream>>>(partials, ROWS_BLOCKS, out);
}

// Round 4
// 99.563 us; speedup vs baseline: 1.1687x; 1.1687x over previous
//
#include <hip/hip_runtime.h>
#include <math.h>

// B=65536 rows, N=1024 cols, fp32.
//   t_b = argmax_c target[b,c]  (first-max tie-break)
//   out = mean_b(-log(y[b,t_b]+1e-8)) + sum_{b,c} w[popc(t_b^c)]*y[b,c]/(B*N),  w[p]=(p==0)?0:6^p
// R3 evidence: latency-bound (hbm 20%, VALU 15%, occ 60%). Fix: 1 cross-lane chain
// per row instead of 3 (lane-private pt acc, owner-lane CE), 2-row ILP.

#define B_ROWS 65536
#define N_COLS 1024
#define WAVES_PER_BLOCK 4
#define ROWS_BLOCKS 2048
#define ROWS_THREADS (WAVES_PER_BLOCK * 64)
#define NWAVES (ROWS_BLOCKS * WAVES_PER_BLOCK)  // 8192 -> 8 rows/wave, 4 ILP2-iters

__device__ __forceinline__ void amax4(float4 v, int c0, float& bv, int& bi) {
    // ascending-column scan within the lane: strict > gives first-index semantics
    if (v.x > bv) { bv = v.x; bi = c0;     }
    if (v.y > bv) { bv = v.y; bi = c0 + 1; }
    if (v.z > bv) { bv = v.z; bi = c0 + 2; }
    if (v.w > bv) { bv = v.w; bi = c0 + 3; }
}

__device__ __forceinline__ float wsum4(const float* w_lds, float4 v, int x) {
    // x = t ^ c0 with c0 % 4 == 0, so t^(c0+e) = x^e
    return w_lds[__popc(x)]     * v.x + w_lds[__popc(x ^ 1)] * v.y +
           w_lds[__popc(x ^ 2)] * v.z + w_lds[__popc(x ^ 3)] * v.w;
}

__device__ __forceinline__ float pick16(float4 v0, float4 v1, float4 v2, float4 v3, int t) {
    // statically-indexed select of element (t>>6 -> which float4 within lane, t&3 -> component)
    const int k = (t >> 2) >> 6;   // 0..3
    const int e = t & 3;
    float4 s = (k & 2) ? ((k & 1) ? v3 : v2) : ((k & 1) ? v1 : v0);
    return (e & 2) ? ((e & 1) ? s.w : s.z) : ((e & 1) ? s.y : s.x);
}

__global__ __launch_bounds__(ROWS_THREADS)
void ce_rows_kernel(const float* __restrict__ y_true,
                    const float* __restrict__ target,
                    float* __restrict__ partials) {
    __shared__ float w_lds[16];
    __shared__ float wave_part[WAVES_PER_BLOCK];

    const int tid = threadIdx.x;
    if (tid < 16) {
        float w = 1.0f;
        for (int p = 0; p < tid; ++p) w *= 6.0f;   // exact: 6^10 < 2^26
        w_lds[tid] = (tid == 0) ? 0.0f : w;
    }
    __syncthreads();

    const int lane  = tid & 63;
    const int wid   = tid >> 6;
    const int gwave = blockIdx.x * WAVES_PER_BLOCK + wid;

    float acc_pt = 0.0f;   // lane-private weighted-sum partial (unscaled)
    float acc_lg = 0.0f;   // lane-private sum of log(y[t]+1e-8) (owner lanes only)

    for (int base = gwave; base < B_ROWS; base += 2 * NWAVES) {
        const int rowA = base;
        const int rowB = base + NWAVES;
        const float4* tA = (const float4*)(target + (size_t)rowA * N_COLS);
        const float4* tB = (const float4*)(target + (size_t)rowB * N_COLS);
        const float4* yA = (const float4*)(y_true + (size_t)rowA * N_COLS);
        const float4* yB = (const float4*)(y_true + (size_t)rowB * N_COLS);

        // issue all 16 coalesced float4 loads up front (addresses independent of t)
        float4 ta0 = tA[lane], ta1 = tA[lane + 64], ta2 = tA[lane + 128], ta3 = tA[lane + 192];
        float4 tb0 = tB[lane], tb1 = tB[lane + 64], tb2 = tB[lane + 128], tb3 = tB[lane + 192];
        float4 ya0 = yA[lane], ya1 = yA[lane + 64], ya2 = yA[lane + 128], ya3 = yA[lane + 192];
        float4 yb0 = yB[lane], yb1 = yB[lane + 64], yb2 = yB[lane + 128], yb3 = yB[lane + 192];

        // local argmax, two independent chains (inputs uniform [0,1) => > -1)
        float bvA = -1.0f, bvB = -1.0f;
        int   biA = 0,     biB = 0;
        amax4(ta0, 4 * lane,         bvA, biA);
        amax4(ta1, 4 * (lane + 64),  bvA, biA);
        amax4(ta2, 4 * (lane + 128), bvA, biA);
        amax4(ta3, 4 * (lane + 192), bvA, biA);
        amax4(tb0, 4 * lane,         bvB, biB);
        amax4(tb1, 4 * (lane + 64),  bvB, biB);
        amax4(tb2, 4 * (lane + 128), bvB, biB);
        amax4(tb3, 4 * (lane + 192), bvB, biB);

        // cross-lane argmax with first-index tie-break; A and B chains overlap
        #pragma unroll
        for (int m = 32; m >= 1; m >>= 1) {
            float ovA = __shfl_xor(bvA, m, 64); int oiA = __shfl_xor(biA, m, 64);
            if (ovA > bvA || (ovA == bvA && oiA < biA)) { bvA = ovA; biA = oiA; }
            float ovB = __shfl_xor(bvB, m, 64); int oiB = __shfl_xor(biB, m, 64);
            if (ovB > bvB || (ovB == bvB && oiB < biB)) { bvB = ovB; biB = oiB; }
        }
        const int tAi = biA;   // wave-uniform
        const int tBi = biB;

        // weighted sums: lane-private accumulation, NO per-row reduction.
        // popc(t^t)=0 -> w=0 excludes the target class automatically.
        acc_pt += wsum4(w_lds, ya0, tAi ^ (4 * lane))
                + wsum4(w_lds, ya1, tAi ^ (4 * (lane + 64)))
                + wsum4(w_lds, ya2, tAi ^ (4 * (lane + 128)))
                + wsum4(w_lds, ya3, tAi ^ (4 * (lane + 192)))
                + wsum4(w_lds, yb0, tBi ^ (4 * lane))
                + wsum4(w_lds, yb1, tBi ^ (4 * (lane + 64)))
                + wsum4(w_lds, yb2, tBi ^ (4 * (lane + 128)))
                + wsum4(w_lds, yb3, tBi ^ (4 * (lane + 192)));

        // CE term: only the lane owning column t computes the log (no shuffle chain)
        if (((tAi >> 2) & 63) == lane)
            acc_lg += logf(pick16(ya0, ya1, ya2, ya3, tAi) + 1e-8f);
        if (((tBi >> 2) & 63) == lane)
            acc_lg += logf(pick16(yb0, yb1, yb2, yb3, tBi) + 1e-8f);
    }

    // single per-wave reduction at the end
    const float invB  = 1.0f / (float)B_ROWS;
    const float invBN = 1.0f / ((float)B_ROWS * (float)N_COLS);
    float val = acc_pt * invBN - acc_lg * invB;
    #pragma unroll
    for (int m = 32; m >= 1; m >>= 1) val += __shfl_xor(val, m, 64);

    if (lane == 0) wave_part[wid] = val;
    __syncthreads();
    if (tid == 0) {
        float s = 0.0f;
        #pragma unroll
        for (int w = 0; w < WAVES_PER_BLOCK; ++w) s += wave_part[w];
        partials[blockIdx.x] = s;
    }
}

__global__ __launch_bounds__(256)
void ce_reduce_kernel(const float* __restrict__ partials, int n, float* __restrict__ out) {
    __shared__ float s[256];
    const int tid = threadIdx.x;
    float a = 0.0f;
    for (int i = tid; i < n; i += 256) a += partials[i];  // fixed order -> deterministic
    s[tid] = a;
    __syncthreads();
    for (int off = 128; off > 0; off >>= 1) {
        if (tid < off) s[tid] += s[tid + off];
        __syncthreads();
    }
    if (tid == 0) out[0] = s[0];
}

extern "C" void kernel_launch(void* const* d_in, const int* in_sizes, int n_in,
                              void* d_out, int out_size, void* d_ws, size_t ws_size,
                              hipStream_t stream) {
    const float* y_true = (const float*)d_in[0];
    const float* target = (const float*)d_in[1];
    float* out = (float*)d_out;
    float* partials = (float*)d_ws;  // ROWS_BLOCKS floats = 8 KB

    ce_rows_kernel<<<ROWS_BLOCKS, ROWS_THREADS, 0, stream>>>(y_true, target, partials);
    ce_reduce_kernel<<<1, 256, 0, stream>>>(partials, ROWS_BLOCKS, out);
}